// Round 14
// baseline (5880.937 us; speedup 1.0000x reference)
//
#include <hip/hip_runtime.h>
#include <hip/hip_bf16.h>

// LSTM: B=64, D=32, H=512, T=1024. gates = [h,x] @ [W_hh;W_ih]^T + b_ih + b_hh
// Round 14: DEDICATED POLLSTER WAVES. 128 blocks (4 groups x 32 slices of 16
// units), 512 threads: waves 0-3 = compute (R12 per-wave pipeline verbatim:
// 4 units, 16 gate rows, 51 MFMAs, W_hi VGPR, W_lo LDS), waves 4-7 = pollster.
// While compute runs step t, pollsters continuously probe gen t+1 packets
// (R12 tag-in-data protocol, coherent dwordx4 sc0 sc1) and stage fresh ones
// into hs[(t+1)&1]. Compute writes its OWN units' h directly to LDS (no L3
// self round-trip) + publishes packets for peers. ONE barrier/step swaps
// buffers -> exchange latency overlaps compute instead of serializing.
// Lockstep safety: each block is both producer & consumer, so slot gen g+2
// cannot be written before every block consumed gen g (unchanged from R9).

typedef unsigned short ushort_t;
typedef unsigned int   uint_t;
typedef unsigned long long u64_t;
typedef __attribute__((ext_vector_type(8))) short bf16x8;
typedef __attribute__((ext_vector_type(4))) float f32x4;
typedef __attribute__((ext_vector_type(4))) uint_t u32x4;

#define T_STEPS 1024
#define HID     512
#define KDIM    544   // 512 h + 32 x
#define NBLK    128   // 4 groups * 32 slices
#define NTHR    512   // 4 compute waves + 4 pollster waves

__device__ inline ushort_t f2bf(float x) {
    __hip_bfloat16 h = __float2bfloat16(x);
    return *(ushort_t*)&h;
}
__device__ inline float bf2f(ushort_t u) {
    __hip_bfloat16 h = *(__hip_bfloat16*)&u;
    return __bfloat162float(h);
}

__device__ inline f32x4 MFMA(bf16x8 a, bf16x8 b, f32x4 c) {
    return __builtin_amdgcn_mfma_f32_16x16x32_bf16(a, b, c, 0, 0, 0);
}

// coherent 16B load/store (L1+L2 bypass, meets at Infinity Cache)
__device__ inline u32x4 cld16(const void* p) {
    u32x4 v;
    asm volatile("global_load_dwordx4 %0, %1, off sc0 sc1"
                 : "=v"(v) : "v"(p) : "memory");
    return v;
}
__device__ inline void cst16(void* p, u32x4 v) {
    asm volatile("global_store_dwordx4 %0, %1, off sc0 sc1"
                 :: "v"(p), "v"(v) : "memory");
}
__device__ inline void waitvm0() {
    asm volatile("s_waitcnt vmcnt(0)" ::: "memory");
}

// is_tanh: tanh(v)=(1-e)/(1+e), e=2^(-2.885*v); sigmoid(v)=1/(1+e), e=2^(-1.4427*v)
__device__ inline float act_gate(float v, int is_tanh) {
    float vc = fminf(fmaxf(v, -43.f), 43.f);
    float kk = is_tanh ? -2.88539008f : -1.44269504f;
    float e  = __builtin_exp2f(vc * kk);
    float num = is_tanh ? (1.f - e) : 1.f;
    return num * __builtin_amdgcn_rcpf(1.f + e);
}

__device__ inline float sel4(int i, float a, float b, float c, float d) {
    return (i == 0) ? a : (i == 1) ? b : (i == 2) ? c : d;
}

// ---------- prep kernels ----------

__global__ void k_init(uint_t* hx32) {
    int i = blockIdx.x * 256 + threadIdx.x;      // grid 256x256 = 65536
    // init h ring: value ~0 (denormal bf16), tag bit16 = 1 (differs from tag 0
    // expected for gen 1/gen 2) -> no ABA with init data.
    hx32[i] = 0x00010000u;                       // 2*4*128*16 x 16B = 65536 u32
}

__global__ void k_wcat(const float* __restrict__ wih, const float* __restrict__ whh,
                       ushort_t* __restrict__ wh, ushort_t* __restrict__ wl) {
    int r = blockIdx.x;                          // 2048 gate rows
    for (int k = threadIdx.x; k < KDIM; k += 256) {
        float w = (k < 512) ? whh[r * 512 + k] : wih[r * 32 + (k - 512)];
        ushort_t hh = f2bf(w);
        ushort_t ll = f2bf(w - bf2f(hh));
        wh[r * KDIM + k] = hh;
        wl[r * KDIM + k] = ll;
    }
}

// input (B=64, D=32, T=1024) fp32 -> xbuf[t][b][d] bf16 hi/lo
__global__ void k_xbuf(const float* __restrict__ in,
                       ushort_t* __restrict__ xh, ushort_t* __restrict__ xl) {
    __shared__ float tile[64][65];
    int bp = blockIdx.x >> 4;                    // batch pair 0..31
    int tt = blockIdx.x & 15;                    // t tile 0..15
    int t0 = tt * 64;
    int wv = threadIdx.x >> 6, l = threadIdx.x & 63;
    for (int r = wv * 16; r < wv * 16 + 16; r++) {
        int b = bp * 2 + (r >> 5), d = r & 31;
        tile[r][l] = in[(b * 32 + d) * 1024 + t0 + l];
    }
    __syncthreads();
    for (int i = 0; i < 16; i++) {
        int tl = wv * 16 + i;
        float v = tile[l][tl];
        ushort_t hh = f2bf(v);
        ushort_t ll = f2bf(v - bf2f(hh));
        int o = (t0 + tl) * 2048 + bp * 64 + l;  // = t*64*32 + b*32 + d
        xh[o] = hh;
        xl[o] = ll;
    }
}

// out[b][t] = conv_b + sum_s part[(g*32+s)*16 + bl][t]   (b = g*16+bl)
__global__ void k_reduce(const float* __restrict__ part, float* __restrict__ out,
                         const float* __restrict__ cvb) {
    int b = blockIdx.x >> 2;                     // 0..63
    int t = (blockIdx.x & 3) * 256 + threadIdx.x;
    int g = b >> 4, bl = b & 15;
    const float* p = part + ((size_t)(g * 32 * 16 + bl)) * 1024 + t;
    float sum = 0.f;
    #pragma unroll
    for (int s = 0; s < 32; s++) sum += p[(size_t)s * 16 * 1024];
    out[b * 1024 + t] = sum + cvb[0];
}

// ---------- main recurrent kernel ----------

__global__ __launch_bounds__(NTHR, 2) void k_lstm(
    const ushort_t* __restrict__ wh, const ushort_t* __restrict__ wlo,
    const ushort_t* __restrict__ xh, const ushort_t* __restrict__ xl,
    char* hx,
    const float* __restrict__ bih, const float* __restrict__ bhh,
    const float* __restrict__ convw, float* __restrict__ part)
{
    const int tid = threadIdx.x;
    const int w   = tid >> 6;          // wave 0..7
    const int l   = tid & 63;
    const int g   = blockIdx.x >> 5;   // batch group 0..3
    const int s   = blockIdx.x & 31;   // hidden slice 0..31 (16 units each)
    const bool isC = (w < 4);          // compute role
    const int wc  = w & 3;             // compute wave idx 0..3
    const int n   = l & 15;            // B-tile row within wave
    const int q   = l >> 4;            // quad
    const int gtn = n >> 2;            // gate 0..3 (i,f,g,o)
    const int u   = n & 3;             // unit within wave
    const int j   = s * 16 + wc * 4 + u;// hidden unit (compute only)
    const int row = gtn * HID + j;     // gate row (compute only)
    const int b0  = g * 16;
    const int wg  = s * 4 + wc;        // producing-wave id in group, 0..127
    const int rl16 = wc * 16 + n;
    // own-units LDS placement: chunk/quad/dword of wg's 4 units
    const int cOwn = wg >> 3, qOwn = (wg >> 1) & 3, dOwn = wg & 1;

    __shared__ ushort_t bloF[17 * 4 * 64 * 8]; // W_lo frag-contig (69.6 KB)
    __shared__ u64_t    hs[2][4096];           // staged h, dbuf (64 KB)
    __shared__ float    projsh[4][16][64];     // projection partials (16 KB)

    // stage W_lo fragment-contiguous with all 512 threads
    for (int e = tid; e < 17 * 256; e += NTHR) {
        int k = e >> 8, rem = e & 255;
        int qq = rem >> 6, ll = rem & 63;
        int ww = ll >> 4, nn = ll & 15;
        int rowr = (nn >> 2) * HID + s * 16 + ww * 4 + (nn & 3);
        *(bf16x8*)&bloF[((k * 4 + qq) * 64 + ll) * 8] =
            *(const bf16x8*)(wlo + rowr * KDIM + k * 32 + qq * 8);
    }
    // zero hs[0] (h_0 = 0)
    for (int i = tid; i < 4096; i += NTHR) hs[0][i] = 0;

    // compute-wave stationary state
    bf16x8 Bh[17];
    float bias = 0.f, cw = 0.f;
    if (isC) {
        #pragma unroll
        for (int c = 0; c < 17; c++)
            Bh[c] = *(const bf16x8*)(wh + row * KDIM + c * 32 + q * 8);
        bias = bih[row] + bhh[row];
        cw   = convw[j];
    }
    float cst[4] = {0.f, 0.f, 0.f, 0.f};

    // pollster constants: pi in 0..255; packets P = k*256 + pi (k=0..7)
    const int pi  = (w - 4) * 64 + l;            // valid when !isC
    const int pi4 = pi >> 4;
    const int pq  = (pi4 >> 1) & 3, pd = pi4 & 1, pc0 = pi4 >> 3;
    const int m16 = pi & 15;
    // own-block packets have P>>6 == s: P = k*256+pi -> P>>6 = 4k + (pi>>6)
    const int kOwn = ((s & 3) == (pi >> 6)) ? (s >> 2) : -1;

    __syncthreads();

    union frag { u64_t d[2]; bf16x8 v; };

    for (int t = 0; t < T_STEPS; t++) {
        if (isC) {
            // ---------------- compute role ----------------
            frag Ax, Lx;
            {
                int xo = (t * 64 + b0 + n) * 32 + q * 8;
                Ax.v = *(const bf16x8*)(xh + xo);
                Lx.v = *(const bf16x8*)(xl + xo);
            }
            const int buf = t & 1;
            f32x4 a0 = {0,0,0,0}, a1 = {0,0,0,0}, a2 = {0,0,0,0},
                  a3 = {0,0,0,0}, a4 = {0,0,0,0}, a5 = {0,0,0,0};
            #pragma unroll
            for (int c = 0; c < 16; c++) {
                frag Ah, Al;
                int li = ((c * 4 + q) * 16 + n) * 2;
                Ah.v = *(const bf16x8*)&hs[buf][li];
                Al.v = *(const bf16x8*)&hs[buf][li + 2048];
                bf16x8 bl_ = *(const bf16x8*)&bloF[((c * 4 + q) * 64 + rl16) * 8];
                if (c & 1) {
                    a1 = MFMA(Ah.v, Bh[c], a1);
                    a3 = MFMA(Ah.v, bl_,   a3);
                    a5 = MFMA(Al.v, Bh[c], a5);
                } else {
                    a0 = MFMA(Ah.v, Bh[c], a0);
                    a2 = MFMA(Ah.v, bl_,   a2);
                    a4 = MFMA(Al.v, Bh[c], a4);
                }
            }
            {   // x chunk (c=16)
                bf16x8 bl_ = *(const bf16x8*)&bloF[((16 * 4 + q) * 64 + rl16) * 8];
                a0 = MFMA(Ax.v, Bh[16], a0);
                a2 = MFMA(Ax.v, bl_,    a2);
                a4 = MFMA(Lx.v, Bh[16], a4);
            }
            f32x4 D = (a0 + a1) + (a2 + a3) + (a4 + a5);

            // epilogue: publish packets to L3 for peers + write own units to
            // the LDS buffer the pollsters are filling (tagged values, so all
            // consumers see bit-identical h).
            char* dstB = hx + (size_t)((((t + 1) & 1) * 4 + g) * 128 + wg) * 256;
            u64_t* hsN = hs[(t + 1) & 1];
            const uint_t tag32 = ((uint_t)((t >> 1) & 1)) << 16;
            float pr[4];
            #pragma unroll
            for (int r = 0; r < 4; r++) {
                float v   = D[r] + bias;
                float act = act_gate(v, gtn == 2);
                float v4  = __shfl_xor(act, 4);
                float v8  = __shfl_xor(act, 8);
                float v12 = __shfl_xor(v4, 8);
                float iv = sel4(gtn,     act, v4, v8, v12);
                float fv = sel4(gtn ^ 1, act, v4, v8, v12);
                float gv = sel4(gtn ^ 2, act, v4, v8, v12);
                float ov = sel4(gtn ^ 3, act, v4, v8, v12);
                float cc = fv * cst[r] + iv * gv;
                cst[r] = cc;
                float th = act_gate(cc, 1);
                float h  = ov * th;
                pr[r] = cw * h;
                ushort_t hb = f2bf(h);
                uint_t hvp = (uint_t)hb;
                uint_t lvp = (uint_t)f2bf(h - bf2f(hb));
                uint_t ivp = hvp | (lvp << 16);                 // (hi,lo) unit u
                uint_t ip1 = (uint_t)__shfl_xor((int)ivp, 1);   // unit u^1
                uint_t bl2 = (uint_t)__shfl_xor((int)ivp, 2);   // unit u^2
                uint_t bh2 = (uint_t)__shfl_xor((int)ip1, 2);   // unit u^3
                if (n == 0) {
                    u32x4 pkt;
                    pkt[0] = (ivp & ~0x10000u) | tag32;
                    pkt[1] = ip1;
                    pkt[2] = bl2;
                    pkt[3] = (bh2 & ~0x10000u) | tag32;
                    cst16(dstB + (q * 4 + r) * 16, pkt);
                    // own-units LDS write (deinterleaved, same values)
                    uint_t hA = __builtin_amdgcn_perm(pkt[1], pkt[0], 0x05040100u);
                    uint_t hB = __builtin_amdgcn_perm(pkt[3], pkt[2], 0x05040100u);
                    uint_t lA = __builtin_amdgcn_perm(pkt[1], pkt[0], 0x07060302u);
                    uint_t lB = __builtin_amdgcn_perm(pkt[3], pkt[2], 0x07060302u);
                    int li = ((cOwn * 4 + qOwn) * 16 + (q * 4 + r)) * 2 + dOwn;
                    hsN[li]        = (u64_t)hA | ((u64_t)hB << 32);
                    hsN[li + 2048] = (u64_t)lA | ((u64_t)lB << 32);
                }
            }
            // projection partial
            #pragma unroll
            for (int r = 0; r < 4; r++) {
                pr[r] += __shfl_xor(pr[r], 1);
                pr[r] += __shfl_xor(pr[r], 2);
                if (n == 0) projsh[wc][q * 4 + r][t & 63] = pr[r];
            }
        } else {
            // ---------------- pollster role ----------------
            // stage gen t+1 (slot (t+1)&1) into hs[(t+1)&1], continuously
            // re-probing stale packets. Peers publish during our compute
            // team's step-t work, so most rounds overlap compute.
            if (t < T_STEPS - 1) {
                const char* src = hx + (size_t)((((t + 1) & 1) * 4 + g)) * 32768;
                u64_t* hsN = hs[(t + 1) & 1];
                const uint_t exp = ((uint_t)((t >> 1) & 1)) << 16;
                u32x4 pk[8];
                int mask = 0xFF;
                if (kOwn >= 0) mask &= ~(1 << kOwn);
                #pragma unroll
                for (int k = 0; k < 8; k++)
                    if (mask & (1 << k)) pk[k] = cld16(src + (k * 256 + pi) * 16);
                for (;;) {
                    waitvm0();
                    int nm = 0;
                    #pragma unroll
                    for (int k = 0; k < 8; k++) {
                        if (!(mask & (1 << k))) continue;
                        if (((pk[k][0] & 0x10000u) == exp) &&
                            ((pk[k][3] & 0x10000u) == exp)) {
                            // fresh: deinterleave + stage
                            uint_t I0 = pk[k][0], I1 = pk[k][1];
                            uint_t I2 = pk[k][2], I3 = pk[k][3];
                            uint_t hA = __builtin_amdgcn_perm(I1, I0, 0x05040100u);
                            uint_t hB = __builtin_amdgcn_perm(I3, I2, 0x05040100u);
                            uint_t lA = __builtin_amdgcn_perm(I1, I0, 0x07060302u);
                            uint_t lB = __builtin_amdgcn_perm(I3, I2, 0x07060302u);
                            int c  = 2 * k + pc0;
                            int li = ((c * 4 + pq) * 16 + m16) * 2 + pd;
                            hsN[li]        = (u64_t)hA | ((u64_t)hB << 32);
                            hsN[li + 2048] = (u64_t)lA | ((u64_t)lB << 32);
                        } else {
                            pk[k] = cld16(src + (k * 256 + pi) * 16);
                            nm |= 1 << k;
                        }
                    }
                    if (!nm) break;
                    mask = nm;
                }
            }
        }

        __syncthreads();   // buffer swap: hs[(t+1)&1] complete for everyone

        // flush projection partials every 64 steps (coalesced NT bursts)
        if ((t & 63) == 63) {
            float* dpt = part + (size_t)((g * 32 + s) * 16) * 1024 + (t - 63);
            for (int i = tid; i < 1024; i += NTHR) {
                int b = i >> 6, tl = i & 63;
                float v = (projsh[0][b][tl] + projsh[1][b][tl]) +
                          (projsh[2][b][tl] + projsh[3][b][tl]);
                __builtin_nontemporal_store(v, dpt + (size_t)b * 1024 + tl);
            }
            __syncthreads();
        }
    }
}

extern "C" void kernel_launch(void* const* d_in, const int* in_sizes, int n_in,
                              void* d_out, int out_size, void* d_ws, size_t ws_size,
                              hipStream_t stream) {
    const float* in  = (const float*)d_in[0];
    const float* Wih = (const float*)d_in[1];
    const float* Whh = (const float*)d_in[2];
    const float* bih = (const float*)d_in[3];
    const float* bhh = (const float*)d_in[4];
    const float* cvw = (const float*)d_in[5];
    const float* cvb = (const float*)d_in[6];
    float* out = (float*)d_out;

    char* ws = (char*)d_ws;
    ushort_t* wh  = (ushort_t*)ws; ws += (size_t)2048 * KDIM * 2;      // 2,228,224
    ushort_t* wl  = (ushort_t*)ws; ws += (size_t)2048 * KDIM * 2;
    ushort_t* xh  = (ushort_t*)ws; ws += (size_t)1024 * 64 * 32 * 2;   // 4,194,304
    ushort_t* xl  = (ushort_t*)ws; ws += (size_t)1024 * 64 * 32 * 2;
    char*     hx  = ws;            ws += (size_t)2 * 4 * 128 * 16 * 16;// 262,144
    float*    pp  = (float*)ws;    ws += (size_t)128 * 16 * 1024 * 4;  // 8,388,608
    // total ~21.5 MB of ws

    k_init<<<256, 256, 0, stream>>>((uint_t*)hx);
    k_wcat<<<2048, 256, 0, stream>>>(Wih, Whh, wh, wl);
    k_xbuf<<<512, 256, 0, stream>>>(in, xh, xl);
    k_lstm<<<NBLK, NTHR, 0, stream>>>(wh, wl, xh, xl, hx,
                                      bih, bhh, cvw, pp);
    k_reduce<<<256, 256, 0, stream>>>(pp, out, cvb);
}